// Round 4
// baseline (18875.650 us; speedup 1.0000x reference)
//
#include <hip/hip_runtime.h>
#include <hip/hip_bf16.h>

// LSTM: B=512, T=256, H=1024, 2 layers + linear head.
// Kernel k: blocks 0-127 = layer0(t=k) [128x128 tiles], blocks 128-255 = layer1(t=k-1).
// Split-precision f16 MFMA (hi*512 | lo*2^20 weight planes; h hi | lo*2048), fp32 accum.
// v2: global_load_lds staging, XOR-swizzled LDS (swizzle on SOURCE addr, linear dest),
// double-buffered BK=32 tiles, 64x64 per-wave output, 1 wg/CU.

#define B_   512
#define T_   256
#define H_   1024
#define BM   128
#define BH   32        // hidden cols per wg
#define BK   32
#define WSZ  4194304L
#define HBSZ 524288L

#define WHI_SCALE   512.0f
#define WLO_SCALE   1048576.0f
#define HLO_SCALE   2048.0f
#define ACCH_DESC   (1.0f / 512.0f)
#define ACCL_DESC   (1.0f / 1048576.0f)

typedef _Float16 f16;
typedef _Float16 half8 __attribute__((ext_vector_type(8)));
typedef float f32x4 __attribute__((ext_vector_type(4)));

__device__ __forceinline__ float sigmoidf_fast(float x) {
  return 1.0f / (1.0f + __builtin_exp2f(-1.44269504f * x));
}
__device__ __forceinline__ float tanhf_fast(float x) {
  float ax = __builtin_fabsf(x);
  float e = __builtin_exp2f(-2.88539008f * ax);
  float t = (1.0f - e) / (1.0f + e);
  return __builtin_copysignf(t, x);
}

__global__ void prep_kernel(const float* __restrict__ Whh0, const float* __restrict__ Wih1,
                            const float* __restrict__ Whh1,
                            const float* __restrict__ bih0, const float* __restrict__ bhh0,
                            const float* __restrict__ bih1, const float* __restrict__ bhh1,
                            const float* __restrict__ bl,
                            f16* __restrict__ Whh0h, f16* __restrict__ Wih1h, f16* __restrict__ Whh1h,
                            float* __restrict__ b0s, float* __restrict__ b1s,
                            f16* __restrict__ h0a, f16* __restrict__ h1a,
                            float* __restrict__ c0, float* __restrict__ c1,
                            float* __restrict__ y)
{
  const long W = WSZ, HB = HBSZ;
  const long total = 3 * W + 8192 + 4 * HB + 2 * HB + 131072;
  long idx = (long)blockIdx.x * 256 + threadIdx.x;
  long stride = (long)gridDim.x * 256;
  for (long i = idx; i < total; i += stride) {
    long r = i;
    if (r < 3 * W) {
      const float* src; f16* dst;
      if (r < W)          { src = Whh0; dst = Whh0h; }
      else if (r < 2 * W) { src = Wih1; dst = Wih1h; r -= W; }
      else                { src = Whh1; dst = Whh1h; r -= 2 * W; }
      float w = src[r];
      f16 hi = (f16)w;
      float hif = (float)hi;
      dst[r]     = (f16)(hif * WHI_SCALE);
      dst[W + r] = (f16)((w - hif) * WLO_SCALE);
      continue;
    }
    r -= 3 * W;
    if (r < 4096) { b0s[r] = bih0[r] + bhh0[r]; continue; } r -= 4096;
    if (r < 4096) { b1s[r] = bih1[r] + bhh1[r]; continue; } r -= 4096;
    if (r < 2 * HB) { h0a[r] = (f16)0.0f; continue; } r -= 2 * HB;
    if (r < 2 * HB) { h1a[r] = (f16)0.0f; continue; } r -= 2 * HB;
    if (r < HB) { c0[r] = 0.0f; continue; } r -= HB;
    if (r < HB) { c1[r] = 0.0f; continue; } r -= HB;
    y[r] = bl[0];
  }
}

__launch_bounds__(256, 1)
__global__ void step_kernel(int t,
    const float* __restrict__ x,        // [512][256][2]
    const float* __restrict__ Wih0,     // [4096][2]
    const float* __restrict__ Wl,       // [1024]
    const f16* __restrict__ Whh0h,      // [2][4096][1024] hi*512 | lo*2^20
    const f16* __restrict__ Wih1h,
    const f16* __restrict__ Whh1h,
    const float* __restrict__ b0s, const float* __restrict__ b1s,
    f16* __restrict__ h0a, f16* __restrict__ h0b,   // [2][512][1024] hi | lo*2048
    f16* __restrict__ h1a, f16* __restrict__ h1b,
    float* __restrict__ c0, float* __restrict__ c1,
    float* __restrict__ y)              // [512][256]
{
  // LDS: [buf][A|B][row 0..127][128B row-unit = plane-hi 64B | plane-lo 64B], XOR-swizzled.
  __shared__ __align__(16) char smem[2][2][128][128];   // 64 KB

  const int bid = blockIdx.x;
  const int tid = threadIdx.x;
  const bool l1 = bid >= 128;
  const int lb = l1 ? bid - 128 : bid;
  const int mt = lb >> 5;        // 0..3
  const int hs = lb & 31;        // 0..31
  const int r0 = mt * BM;
  const int j0 = hs * BH;

  const f16 *hA, *hB = nullptr;
  const f16 *WA, *WB = nullptr;
  f16* hout; float* cc;
  int tt, NK;
  if (!l1) {
    if (t >= T_) return;
    tt = t;
    hA   = (t & 1) ? h0b : h0a;
    hout = (t & 1) ? h0a : h0b;
    WA = Whh0h;
    cc = c0; NK = H_ / BK;              // 32
  } else {
    if (t == 0) return;
    tt = t - 1;
    hA   = ((tt + 1) & 1) ? h0b : h0a;  // h0(tt)
    hB   = (tt & 1) ? h1b : h1a;        // h1(tt-1)
    hout = ((tt + 1) & 1) ? h1b : h1a;  // h1(tt)
    WA = Wih1h; WB = Whh1h;
    cc = c1; NK = 2 * H_ / BK;          // 64
  }

  const int lane = tid & 63;
  const int wv = tid >> 6;       // 0..3
  const int wvm = wv >> 1;       // 0..1 (M half)
  const int wvn = wv & 1;        // 0..1 (N half)
  const int ln15 = lane & 15;

  // ---- staging lane constants (chunk = 1KB = 8 rows x 128B row-unit) ----
  const int rsub  = lane >> 3;          // 0..7  (== row & 7 within chunk)
  const int ubl   = (lane & 7) << 4;    // 0..112, byte within 128B row-unit
  const int ubs   = ubl ^ (rsub << 4);  // inverse-swizzled logical byte
  const int spl   = ubs >> 6;           // plane 0=hi 1=lo
  const int skb   = ubs & 63;           // byte within 64B k-chunk

  f32x4 accH[4][4] = {};
  f32x4 accL[4][4] = {};

  auto stage = [&](int ki, int buf) {
    const f16* hsrc; const f16* wsrc; long ko2;
    if (!l1 || ki < 32) { hsrc = hA; wsrc = WA; ko2 = (long)ki * BK * 2; }
    else                { hsrc = hB; wsrc = WB; ko2 = (long)(ki - 32) * BK * 2; }
    const long aPl = spl ? HBSZ * 2 : 0;
    const long bPl = spl ? WSZ * 2 : 0;
    #pragma unroll
    for (int n = 0; n < 8; n++) {
      const int c = wv * 8 + n;          // 0..31: 0-15 A chunks, 16-31 B chunks
      long gbyte; const char* srcb; char* dst;
      if (c < 16) {
        int row = c * 8 + rsub;          // tile row 0..127
        gbyte = aPl + (long)(r0 + row) * 2048 + ko2 + skb;
        srcb = (const char*)hsrc;
        dst = &smem[buf][0][c * 8][0];
      } else {
        int row = (c - 16) * 8 + rsub;
        int gate = (row >> 4) & 3, sub = row >> 6;
        int wrow = gate * H_ + j0 + sub * 16 + (row & 15);
        gbyte = bPl + (long)wrow * 2048 + ko2 + skb;
        srcb = (const char*)wsrc;
        dst = &smem[buf][1][(c - 16) * 8][0];
      }
      __builtin_amdgcn_global_load_lds(
          (const __attribute__((address_space(1))) void*)(srcb + gbyte),
          (__attribute__((address_space(3))) void*)dst, 16, 0, 0);
    }
  };

  const int kqb = (lane >> 4) << 4;          // 0,16,32,48: byte offset of 8-f16 k-group
  const int swz = (ln15 & 7) << 4;           // row&7 == ln15&7 for all frag rows
  const int uhi = kqb ^ swz;                 // plane-hi swizzled byte
  const int ulo = (64 | kqb) ^ swz;          // plane-lo swizzled byte

  auto compute = [&](int buf) {
    const char* base = &smem[buf][0][0][0];
    half8 ah[4], al[4], bh[4], blo[4];
    #pragma unroll
    for (int mi = 0; mi < 4; mi++) {
      int row = wvm * 64 + mi * 16 + ln15;
      ah[mi] = *(const half8*)(base + row * 128 + uhi);
      al[mi] = *(const half8*)(base + row * 128 + ulo);
    }
    #pragma unroll
    for (int ni = 0; ni < 4; ni++) {
      int row = wvn * 64 + ni * 16 + ln15;
      bh[ni]  = *(const half8*)(base + 16384 + row * 128 + uhi);
      blo[ni] = *(const half8*)(base + 16384 + row * 128 + ulo);
    }
    #pragma unroll
    for (int mi = 0; mi < 4; mi++)
      #pragma unroll
      for (int ni = 0; ni < 4; ni++) {
        accH[mi][ni] = __builtin_amdgcn_mfma_f32_16x16x32_f16(ah[mi], bh[ni],  accH[mi][ni], 0, 0, 0);
        accL[mi][ni] = __builtin_amdgcn_mfma_f32_16x16x32_f16(ah[mi], blo[ni], accL[mi][ni], 0, 0, 0);
        accL[mi][ni] = __builtin_amdgcn_mfma_f32_16x16x32_f16(al[mi], bh[ni],  accL[mi][ni], 0, 0, 0);
      }
  };

  // ---- 2-phase double-buffered K loop ----
  stage(0, 0);
  __syncthreads();
  int buf = 0;
  for (int ki = 0; ki < NK; ki++) {
    if (ki + 1 < NK) stage(ki + 1, buf ^ 1);
    compute(buf);
    __syncthreads();
    buf ^= 1;
  }

  // ---------------- epilogue: LSTM cell, fully in-register ----------------
  const int j = j0 + wvn * 16 + ln15;
  const float* bs = l1 ? b1s : b0s;
  float bsum[4], wi0[4][2];
  #pragma unroll
  for (int g = 0; g < 4; g++) bsum[g] = bs[g * H_ + j];
  if (!l1) {
    #pragma unroll
    for (int g = 0; g < 4; g++) {
      wi0[g][0] = Wih0[(g * H_ + j) * 2 + 0];
      wi0[g][1] = Wih0[(g * H_ + j) * 2 + 1];
    }
  }
  const float wl = l1 ? Wl[j] : 0.0f;
  const int grp = (lane >> 4) & 3;

  #pragma unroll
  for (int mi = 0; mi < 4; mi++) {
    #pragma unroll
    for (int r = 0; r < 4; r++) {
      int row = r0 + wvm * 64 + mi * 16 + grp * 4 + r;
      float gi = accH[mi][0][r] * ACCH_DESC + accL[mi][0][r] * ACCL_DESC + bsum[0];
      float gf = accH[mi][1][r] * ACCH_DESC + accL[mi][1][r] * ACCL_DESC + bsum[1];
      float gg = accH[mi][2][r] * ACCH_DESC + accL[mi][2][r] * ACCL_DESC + bsum[2];
      float go = accH[mi][3][r] * ACCH_DESC + accL[mi][3][r] * ACCL_DESC + bsum[3];
      if (!l1) {
        float x0 = x[(row * T_ + tt) * 2 + 0];
        float x1 = x[(row * T_ + tt) * 2 + 1];
        gi += x0 * wi0[0][0] + x1 * wi0[0][1];
        gf += x0 * wi0[1][0] + x1 * wi0[1][1];
        gg += x0 * wi0[2][0] + x1 * wi0[2][1];
        go += x0 * wi0[3][0] + x1 * wi0[3][1];
      }
      float ig = sigmoidf_fast(gi);
      float fg = sigmoidf_fast(gf);
      float gv = tanhf_fast(gg);
      float ov = sigmoidf_fast(go);
      int cidx = row * H_ + j;
      float cn = fg * cc[cidx] + ig * gv;
      cc[cidx] = cn;
      float hn = ov * tanhf_fast(cn);
      f16 hhi = (f16)hn;
      hout[cidx] = hhi;
      hout[cidx + HBSZ] = (f16)((hn - (float)hhi) * HLO_SCALE);
      if (l1) {
        float yp = hn * wl;
        #pragma unroll
        for (int s = 1; s < 16; s <<= 1) yp += __shfl_xor(yp, s, 64);
        if (ln15 == 0) atomicAdd(&y[row * T_ + tt], yp);
      }
    }
  }
}

extern "C" void kernel_launch(void* const* d_in, const int* in_sizes, int n_in,
                              void* d_out, int out_size, void* d_ws, size_t ws_size,
                              hipStream_t stream) {
  (void)in_sizes; (void)n_in; (void)out_size; (void)ws_size;
  const float* x    = (const float*)d_in[0];
  const float* Wih0 = (const float*)d_in[1];
  const float* Whh0 = (const float*)d_in[2];
  const float* bih0 = (const float*)d_in[3];
  const float* bhh0 = (const float*)d_in[4];
  const float* Wih1 = (const float*)d_in[5];
  const float* Whh1 = (const float*)d_in[6];
  const float* bih1 = (const float*)d_in[7];
  const float* bhh1 = (const float*)d_in[8];
  const float* Wl   = (const float*)d_in[9];
  const float* bl   = (const float*)d_in[10];
  float* y = (float*)d_out;

  char* ws = (char*)d_ws;
  size_t off = 0;
  auto alloc = [&](size_t bytes) { char* p = ws + off; off += (bytes + 255) & ~255UL; return p; };
  f16*   Whh0h = (f16*)alloc(2 * WSZ * sizeof(f16));   // hi*512 | lo*2^20
  f16*   Wih1h = (f16*)alloc(2 * WSZ * sizeof(f16));
  f16*   Whh1h = (f16*)alloc(2 * WSZ * sizeof(f16));
  float* b0s   = (float*)alloc(4096 * sizeof(float));
  float* b1s   = (float*)alloc(4096 * sizeof(float));
  f16*   h0a   = (f16*)alloc(2 * HBSZ * sizeof(f16));  // hi | lo*2048
  f16*   h0b   = (f16*)alloc(2 * HBSZ * sizeof(f16));
  f16*   h1a   = (f16*)alloc(2 * HBSZ * sizeof(f16));
  f16*   h1b   = (f16*)alloc(2 * HBSZ * sizeof(f16));
  float* c0    = (float*)alloc(HBSZ * sizeof(float));
  float* c1    = (float*)alloc(HBSZ * sizeof(float));

  hipLaunchKernelGGL(prep_kernel, dim3(2048), dim3(256), 0, stream,
      Whh0, Wih1, Whh1, bih0, bhh0, bih1, bhh1, bl,
      Whh0h, Wih1h, Whh1h, b0s, b1s, h0a, h1a, c0, c1, y);

  for (int t = 0; t <= T_; t++) {
    hipLaunchKernelGGL(step_kernel, dim3(256), dim3(256), 0, stream, t,
        x, Wih0, Wl, Whh0h, Wih1h, Whh1h, b0s, b1s,
        h0a, h0b, h1a, h1b, c0, c1, y);
  }
}